// Round 3
// baseline (77.511 us; speedup 1.0000x reference)
//
#include <hip/hip_runtime.h>
#include <math.h>

#define NB   8
#define SEQ  2048
#define EMB  8
#define NH   4
#define NFF  2048
#define NTOK (NB*SEQ)          // 16384
#define LNEPS 1e-5f

__device__ __forceinline__ float dot8(const float4& a, const float4& b,
                                      const float4& c, const float4& d) {
    return a.x*b.x + a.y*b.y + a.z*b.z + a.w*b.w
         + c.x*d.x + c.y*d.y + c.z*d.z + c.w*d.w;
}

// ---------------------------------------------------------------------------
// projH[(b*4+h)][s][2] = (x @ Wp^T) head-major, and W2T[f][e] = W2[e][f]
// ---------------------------------------------------------------------------
__global__ __launch_bounds__(256) void k_prep(const float* __restrict__ x,
                                              const float* __restrict__ Wp,
                                              const float* __restrict__ W2,
                                              float* __restrict__ projH,
                                              float* __restrict__ w2t) {
    int t = blockIdx.x * 256 + threadIdx.x;
    if (t < NTOK) {
        int b = t >> 11, s = t & (SEQ - 1);
        const float4* xr = (const float4*)(x + (size_t)t * EMB);
        float4 xa = xr[0], xb = xr[1];
        float o[8];
#pragma unroll
        for (int e = 0; e < 8; ++e) {
            const float4* wr = (const float4*)(Wp + e * EMB);
            o[e] = dot8(xa, wr[0], xb, wr[1]);
        }
#pragma unroll
        for (int h = 0; h < 4; ++h) {
            *(float2*)(projH + ((size_t)(b * 4 + h) * SEQ + s) * 2) =
                make_float2(o[2 * h], o[2 * h + 1]);
        }
    }
    if (t < NFF) {
        float o[8];
#pragma unroll
        for (int e = 0; e < 8; ++e) o[e] = W2[e * NFF + t];
        float4* wr = (float4*)(w2t + (size_t)t * EMB);
        wr[0] = make_float4(o[0], o[1], o[2], o[3]);
        wr[1] = make_float4(o[4], o[5], o[6], o[7]);
    }
}

// ---------------------------------------------------------------------------
// attention, one (b,h) per 64 blocks.  q=k=v = projH[bh].  No-max softmax
// (scores bounded, fp32-safe): partials over key-subranges combine linearly.
// Block: 256 thr = 8 key-subranges(256 keys) x 32 queries.  grid = 2048
// (8 blocks/CU -> 8 waves/SIMD).  K staged coalesced (head-major, 16KB).
// ---------------------------------------------------------------------------
#define QC 32
__global__ __launch_bounds__(256) void k_attn(const float* __restrict__ projH,
                                              float* __restrict__ ctx) {
    __shared__ float4 KsRaw[SEQ / 2];       // 16 KB
    __shared__ float red[3][8][QC];         // 3 KB, conflict-free layout

    int bid = blockIdx.x;
    int qc  = bid & 63;                     // 64 query chunks of 32
    int bh  = bid >> 6;                     // (b*4+h)

    const float4* gsr = (const float4*)(projH + (size_t)bh * SEQ * 2);
#pragma unroll
    for (int i = 0; i < 4; ++i)
        KsRaw[threadIdx.x + 256 * i] = gsr[threadIdx.x + 256 * i];
    __syncthreads();

    const float2* Ks = (const float2*)KsRaw;
    int ql  = threadIdx.x & 31;
    int sub = threadIdx.x >> 5;             // 8 subranges, uniform per half-wave
    int qi  = qc * QC + ql;

    float2 q = Ks[qi];
    const float K2E = 1.02001595929984f;    // log2(e)/sqrt(DK)
    float qx = q.x * K2E, qy = q.y * K2E;

    float l0 = 0.f, a0 = 0.f, a1 = 0.f;     // even-key accumulators
    float l1 = 0.f, b0 = 0.f, b1 = 0.f;     // odd-key accumulators
    int j0 = sub * (SEQ / 8);
#pragma unroll 8
    for (int jj = 0; jj < SEQ / 8; jj += 2) {
        float2 k0 = Ks[j0 + jj];            // merged ds_read_b128
        float2 k1 = Ks[j0 + jj + 1];
        float s0 = fmaf(qy, k0.y, qx * k0.x);
        float s1 = fmaf(qy, k1.y, qx * k1.x);
        float p0 = exp2f(s0);
        float p1 = exp2f(s1);
        l0 += p0;               l1 += p1;
        a0 = fmaf(p0, k0.x, a0); b0 = fmaf(p1, k1.x, b0);
        a1 = fmaf(p0, k0.y, a1); b1 = fmaf(p1, k1.y, b1);
    }
    red[0][sub][ql] = l0 + l1;
    red[1][sub][ql] = a0 + b0;
    red[2][sub][ql] = a1 + b1;
    __syncthreads();

    if (threadIdx.x < QC) {
        float L = 0.f, A0 = 0.f, A1 = 0.f;
#pragma unroll
        for (int s = 0; s < 8; ++s) {
            L  += red[0][s][threadIdx.x];
            A0 += red[1][s][threadIdx.x];
            A1 += red[2][s][threadIdx.x];
        }
        float inv = 1.0f / L;
        int b = bh >> 2, h = bh & 3;
        int qg = qc * QC + threadIdx.x;
        *(float2*)(ctx + ((size_t)b * SEQ + qg) * EMB + 2 * h) =
            make_float2(A0 * inv, A1 * inv);
    }
}

// ---------------------------------------------------------------------------
// attn_out = ctx @ Wo^T ; x1 = LN1(x + attn_out) ; outq = cumprod(cos(x1))
// ---------------------------------------------------------------------------
__global__ __launch_bounds__(256) void k_post(const float* __restrict__ ctx,
                                              const float* __restrict__ x,
                                              const float* __restrict__ Wo,
                                              const float* __restrict__ g1,
                                              const float* __restrict__ b1,
                                              float* __restrict__ x1,
                                              float* __restrict__ outq) {
    int t = blockIdx.x * 256 + threadIdx.x;
    if (t >= NTOK) return;

    const float4* cr = (const float4*)(ctx + (size_t)t * EMB);
    float4 ca = cr[0], cb = cr[1];
    const float4* xr = (const float4*)(x + (size_t)t * EMB);
    float4 xa = xr[0], xb = xr[1];

    float y[8], s = 0.f;
#pragma unroll
    for (int e = 0; e < 8; ++e) {
        const float4* wr = (const float4*)(Wo + e * EMB);
        float ao = dot8(ca, wr[0], cb, wr[1]);
        float xv = (e < 4) ? ((const float*)&xa)[e] : ((const float*)&xb)[e - 4];
        y[e] = xv + ao;
        s += y[e];
    }
    float mu = s * 0.125f, vs = 0.f;
#pragma unroll
    for (int e = 0; e < 8; ++e) { float d = y[e] - mu; vs += d * d; }
    float r = rsqrtf(vs * 0.125f + LNEPS);

    float xo[8], qo[8], cp = 1.f;
#pragma unroll
    for (int e = 0; e < 8; ++e) {
        float v = (y[e] - mu) * r * g1[e] + b1[e];
        xo[e] = v;
        cp *= __cosf(v);
        qo[e] = cp;
    }
    float4* x1r = (float4*)(x1 + (size_t)t * EMB);
    x1r[0] = make_float4(xo[0], xo[1], xo[2], xo[3]);
    x1r[1] = make_float4(xo[4], xo[5], xo[6], xo[7]);
    float4* qr = (float4*)(outq + (size_t)t * EMB);
    qr[0] = make_float4(qo[0], qo[1], qo[2], qo[3]);
    qr[1] = make_float4(qo[4], qo[5], qo[6], qo[7]);
}

// ---------------------------------------------------------------------------
// h = relu(outq @ W1^T + bb1); ffn = h @ W2^T + bb2; out = LN2(x1 + ffn)
// 32 tokens/block (grid=512), thread = (tg: 4 tokens) x (sub: 64-wide
// f-chunk).  One W-row pair load feeds 4 tokens for ILP.  LDS reduce,
// LN2 via 8-lane shuffles.
// ---------------------------------------------------------------------------
#define TB   32                 // tokens per block
#define NSUB 32                 // f subranges
#define FCH  (NFF / NSUB)       // 64 f per thread
__global__ __launch_bounds__(256) void k_ffn(const float* __restrict__ outq,
                                             const float* __restrict__ x1,
                                             const float* __restrict__ W1,
                                             const float* __restrict__ bb1,
                                             const float* __restrict__ w2t,
                                             const float* __restrict__ bb2,
                                             const float* __restrict__ g2,
                                             const float* __restrict__ b2,
                                             float* __restrict__ out) {
    __shared__ float red[NSUB][TB + 1][8];

    int tg   = threadIdx.x & 7;             // 8 token groups x 4 tokens
    int sub  = threadIdx.x >> 3;            // 32 f-subranges
    int tok0 = blockIdx.x * TB + tg * 4;

    float4 qa[4], qb[4];
#pragma unroll
    for (int k = 0; k < 4; ++k) {
        const float4* qr = (const float4*)(outq + (size_t)(tok0 + k) * EMB);
        qa[k] = qr[0];
        qb[k] = qr[1];
    }

    float acc[4][8];
#pragma unroll
    for (int k = 0; k < 4; ++k)
#pragma unroll
        for (int e = 0; e < 8; ++e) acc[k][e] = 0.f;

    int f0 = sub * FCH;
#pragma unroll 2
    for (int i = 0; i < FCH; ++i) {
        int f = f0 + i;
        const float4* w1r = (const float4*)(W1 + (size_t)f * EMB);
        float4 wa = w1r[0], wb = w1r[1];
        float bias = bb1[f];
        const float4* w2r = (const float4*)(w2t + (size_t)f * EMB);
        float4 va = w2r[0], vb = w2r[1];
#pragma unroll
        for (int k = 0; k < 4; ++k) {
            float hv = fmaxf(dot8(qa[k], wa, qb[k], wb) + bias, 0.f);
            acc[k][0] = fmaf(hv, va.x, acc[k][0]);
            acc[k][1] = fmaf(hv, va.y, acc[k][1]);
            acc[k][2] = fmaf(hv, va.z, acc[k][2]);
            acc[k][3] = fmaf(hv, va.w, acc[k][3]);
            acc[k][4] = fmaf(hv, vb.x, acc[k][4]);
            acc[k][5] = fmaf(hv, vb.y, acc[k][5]);
            acc[k][6] = fmaf(hv, vb.z, acc[k][6]);
            acc[k][7] = fmaf(hv, vb.w, acc[k][7]);
        }
    }
#pragma unroll
    for (int k = 0; k < 4; ++k) {
        float4* dst = (float4*)&red[sub][tg * 4 + k][0];
        dst[0] = make_float4(acc[k][0], acc[k][1], acc[k][2], acc[k][3]);
        dst[1] = make_float4(acc[k][4], acc[k][5], acc[k][6], acc[k][7]);
    }
    __syncthreads();

    int rtok = threadIdx.x >> 3;
    int re   = threadIdx.x & 7;
    float v = 0.f;
#pragma unroll
    for (int s = 0; s < NSUB; ++s) v += red[s][rtok][re];
    int tok = blockIdx.x * TB + rtok;
    v += bb2[re] + x1[(size_t)tok * EMB + re];

    float s8 = v;
    s8 += __shfl_xor(s8, 1);
    s8 += __shfl_xor(s8, 2);
    s8 += __shfl_xor(s8, 4);
    float mu = s8 * 0.125f;
    float d  = v - mu;
    float vs = d * d;
    vs += __shfl_xor(vs, 1);
    vs += __shfl_xor(vs, 2);
    vs += __shfl_xor(vs, 4);
    float r = rsqrtf(vs * 0.125f + LNEPS);
    out[(size_t)tok * EMB + re] = d * r * g2[re] + b2[re];
}

// ---------------------------------------------------------------------------
extern "C" void kernel_launch(void* const* d_in, const int* in_sizes, int n_in,
                              void* d_out, int out_size, void* d_ws, size_t ws_size,
                              hipStream_t stream) {
    const float* x   = (const float*)d_in[0];
    const float* Wp  = (const float*)d_in[1];
    const float* Wo  = (const float*)d_in[2];
    const float* g1  = (const float*)d_in[3];
    const float* b1  = (const float*)d_in[4];
    const float* W1  = (const float*)d_in[5];
    const float* bb1 = (const float*)d_in[6];
    const float* W2  = (const float*)d_in[7];
    const float* bb2 = (const float*)d_in[8];
    const float* g2  = (const float*)d_in[9];
    const float* b2  = (const float*)d_in[10];
    float* out = (float*)d_out;

    float* ws    = (float*)d_ws;
    float* projH = ws;                // 131072 f32 (head-major)
    float* ctx   = ws + 131072;       // 131072 f32
    float* x1    = ws + 262144;       // 131072 f32
    float* outq  = ws + 393216;       // 131072 f32
    float* w2t   = ws + 524288;       // 16384 f32

    hipLaunchKernelGGL(k_prep, dim3(NTOK / 256), dim3(256), 0, stream,
                       x, Wp, W2, projH, w2t);
    hipLaunchKernelGGL(k_attn, dim3(NB * NH * (SEQ / QC)), dim3(256), 0, stream,
                       projH, ctx);
    hipLaunchKernelGGL(k_post, dim3(NTOK / 256), dim3(256), 0, stream,
                       ctx, x, Wo, g1, b1, x1, outq);
    hipLaunchKernelGGL(k_ffn, dim3(NTOK / TB), dim3(256), 0, stream,
                       outq, x1, W1, bb1, w2t, bb2, g2, b2, out);
}

// Round 5
// 70.377 us; speedup vs baseline: 1.1014x; 1.1014x over previous
//
#include <hip/hip_runtime.h>
#include <math.h>

#define NB   8
#define SEQ  2048
#define EMB  8
#define NH   4
#define NFF  2048
#define NTOK (NB*SEQ)          // 16384
#define LNEPS 1e-5f

__device__ __forceinline__ float dot8(const float4& a, const float4& b,
                                      const float4& c, const float4& d) {
    return a.x*b.x + a.y*b.y + a.z*b.z + a.w*b.w
         + c.x*d.x + c.y*d.y + c.z*d.z + c.w*d.w;
}

// ---------------------------------------------------------------------------
// projH[(b*4+h)][s][2] = (x @ Wp^T) head-major, and W2T[f][e] = W2[e][f]
// ---------------------------------------------------------------------------
__global__ __launch_bounds__(256) void k_prep(const float* __restrict__ x,
                                              const float* __restrict__ Wp,
                                              const float* __restrict__ W2,
                                              float* __restrict__ projH,
                                              float* __restrict__ w2t) {
    int t = blockIdx.x * 256 + threadIdx.x;
    if (t < NTOK) {
        int b = t >> 11, s = t & (SEQ - 1);
        const float4* xr = (const float4*)(x + (size_t)t * EMB);
        float4 xa = xr[0], xb = xr[1];
        float o[8];
#pragma unroll
        for (int e = 0; e < 8; ++e) {
            const float4* wr = (const float4*)(Wp + e * EMB);
            o[e] = dot8(xa, wr[0], xb, wr[1]);
        }
#pragma unroll
        for (int h = 0; h < 4; ++h) {
            *(float2*)(projH + ((size_t)(b * 4 + h) * SEQ + s) * 2) =
                make_float2(o[2 * h], o[2 * h + 1]);
        }
    }
    if (t < NFF) {
        float o[8];
#pragma unroll
        for (int e = 0; e < 8; ++e) o[e] = W2[e * NFF + t];
        float4* wr = (float4*)(w2t + (size_t)t * EMB);
        wr[0] = make_float4(o[0], o[1], o[2], o[3]);
        wr[1] = make_float4(o[4], o[5], o[6], o[7]);
    }
}

// ---------------------------------------------------------------------------
// attention, one (b,h) per 64 blocks.  q=k=v = projH[bh].  No-max softmax
// (scores bounded ~|s|<10, fp32-safe): key-subrange partials combine
// linearly.  Block: 256 thr = 8 key-subranges(256 keys) x 32 queries,
// grid 2048 (8 blocks/CU).  K staged in LDS as SoA, PRE-SCALED by 1/sqrt(2)
// (q rescaled by sqrt(2) at read; sqrt(2) folded back via 1/L at the end),
// so the per-key score is mul+fma and __expf keeps R2-proven numerics.
// Per key: 6 VALU + 1 trans.
// ---------------------------------------------------------------------------
#define QC 32
__global__ __launch_bounds__(256) void k_attn(const float* __restrict__ projH,
                                              float* __restrict__ ctx) {
    __shared__ float Kx[SEQ];               // 8 KB  (pre-scaled by 1/sqrt2)
    __shared__ float Ky[SEQ];               // 8 KB
    __shared__ float red[3][8][QC];         // 3 KB

    int bid = blockIdx.x;
    int qc  = bid & 63;                     // 64 query chunks of 32
    int bh  = bid >> 6;                     // (b*4+h)

    const float SC = 0.70710678118654752f; // 1/sqrt(DK)
    const float4* gsr = (const float4*)(projH + (size_t)bh * SEQ * 2);
    for (int i = threadIdx.x; i < SEQ / 2; i += 256) {
        float4 v = gsr[i];                  // keys 2i,2i+1: (x0,y0,x1,y1)
        *(float2*)&Kx[2 * i] = make_float2(v.x * SC, v.z * SC);
        *(float2*)&Ky[2 * i] = make_float2(v.y * SC, v.w * SC);
    }
    __syncthreads();

    int ql  = threadIdx.x & 31;
    int sub = threadIdx.x >> 5;             // 8 subranges, uniform per half-wave
    int qi  = qc * QC + ql;

    const float SQ2 = 1.41421356237309505f;
    float qx = Kx[qi] * SQ2, qy = Ky[qi] * SQ2;  // q unscaled again

    // two accumulator groups for dep-chain ILP
    float l0 = 0.f, ax0 = 0.f, ay0 = 0.f;
    float l1 = 0.f, ax1 = 0.f, ay1 = 0.f;

    const float4* Kx4 = (const float4*)Kx;
    const float4* Ky4 = (const float4*)Ky;
    int j04 = sub * (SEQ / 8 / 4);          // 64 float4 groups per subrange
#pragma unroll 4
    for (int jj = 0; jj < SEQ / 8 / 4; ++jj) {
        float4 kx = Kx4[j04 + jj];          // broadcast reads: no conflicts
        float4 ky = Ky4[j04 + jj];
        float s0 = fmaf(qy, ky.x, qx * kx.x);
        float s1 = fmaf(qy, ky.y, qx * kx.y);
        float s2 = fmaf(qy, ky.z, qx * kx.z);
        float s3 = fmaf(qy, ky.w, qx * kx.w);
        float p0 = __expf(s0);
        float p1 = __expf(s1);
        float p2 = __expf(s2);
        float p3 = __expf(s3);
        l0 += p0;                l1 += p1;
        ax0 = fmaf(p0, kx.x, ax0); ax1 = fmaf(p1, kx.y, ax1);
        ay0 = fmaf(p0, ky.x, ay0); ay1 = fmaf(p1, ky.y, ay1);
        l0 += p2;                l1 += p3;
        ax0 = fmaf(p2, kx.z, ax0); ax1 = fmaf(p3, kx.w, ax1);
        ay0 = fmaf(p2, ky.z, ay0); ay1 = fmaf(p3, ky.w, ay1);
    }
    red[0][sub][ql] = l0 + l1;
    red[1][sub][ql] = ax0 + ax1;
    red[2][sub][ql] = ay0 + ay1;
    __syncthreads();

    if (threadIdx.x < QC) {
        float L = 0.f, A0 = 0.f, A1 = 0.f;
#pragma unroll
        for (int s = 0; s < 8; ++s) {
            L  += red[0][s][threadIdx.x];
            A0 += red[1][s][threadIdx.x];
            A1 += red[2][s][threadIdx.x];
        }
        float inv = SQ2 / L;                // undo the 1/sqrt2 on staged k
        int b = bh >> 2, h = bh & 3;
        int qg = qc * QC + threadIdx.x;
        *(float2*)(ctx + ((size_t)b * SEQ + qg) * EMB + 2 * h) =
            make_float2(A0 * inv, A1 * inv);
    }
}

// ---------------------------------------------------------------------------
// attn_out = ctx @ Wo^T ; x1 = LN1(x + attn_out) ; outq = cumprod(cos(x1))
// ---------------------------------------------------------------------------
__global__ __launch_bounds__(256) void k_post(const float* __restrict__ ctx,
                                              const float* __restrict__ x,
                                              const float* __restrict__ Wo,
                                              const float* __restrict__ g1,
                                              const float* __restrict__ b1,
                                              float* __restrict__ x1,
                                              float* __restrict__ outq) {
    int t = blockIdx.x * 256 + threadIdx.x;
    if (t >= NTOK) return;

    const float4* cr = (const float4*)(ctx + (size_t)t * EMB);
    float4 ca = cr[0], cb = cr[1];
    const float4* xr = (const float4*)(x + (size_t)t * EMB);
    float4 xa = xr[0], xb = xr[1];

    float y[8], s = 0.f;
#pragma unroll
    for (int e = 0; e < 8; ++e) {
        const float4* wr = (const float4*)(Wo + e * EMB);
        float ao = dot8(ca, wr[0], cb, wr[1]);
        float xv = (e < 4) ? ((const float*)&xa)[e] : ((const float*)&xb)[e - 4];
        y[e] = xv + ao;
        s += y[e];
    }
    float mu = s * 0.125f, vs = 0.f;
#pragma unroll
    for (int e = 0; e < 8; ++e) { float d = y[e] - mu; vs += d * d; }
    float r = rsqrtf(vs * 0.125f + LNEPS);

    float xo[8], qo[8], cp = 1.f;
#pragma unroll
    for (int e = 0; e < 8; ++e) {
        float v = (y[e] - mu) * r * g1[e] + b1[e];
        xo[e] = v;
        cp *= __cosf(v);
        qo[e] = cp;
    }
    float4* x1r = (float4*)(x1 + (size_t)t * EMB);
    x1r[0] = make_float4(xo[0], xo[1], xo[2], xo[3]);
    x1r[1] = make_float4(xo[4], xo[5], xo[6], xo[7]);
    float4* qr = (float4*)(outq + (size_t)t * EMB);
    qr[0] = make_float4(qo[0], qo[1], qo[2], qo[3]);
    qr[1] = make_float4(qo[4], qo[5], qo[6], qo[7]);
}

// ---------------------------------------------------------------------------
// h = relu(outq @ W1^T + bb1); ffn = h @ W2^T + bb2; out = LN2(x1 + ffn)
// 32 tokens/block (grid=512), thread = (tg: 4 tokens) x (sub: 64-wide
// f-chunk).  LDS reduce, LN2 via 8-lane shuffles.
// ---------------------------------------------------------------------------
#define TB   32                 // tokens per block
#define NSUB 32                 // f subranges
#define FCH  (NFF / NSUB)       // 64 f per thread
__global__ __launch_bounds__(256) void k_ffn(const float* __restrict__ outq,
                                             const float* __restrict__ x1,
                                             const float* __restrict__ W1,
                                             const float* __restrict__ bb1,
                                             const float* __restrict__ w2t,
                                             const float* __restrict__ bb2,
                                             const float* __restrict__ g2,
                                             const float* __restrict__ b2,
                                             float* __restrict__ out) {
    __shared__ float red[NSUB][TB + 1][8];

    int tg   = threadIdx.x & 7;             // 8 token groups x 4 tokens
    int sub  = threadIdx.x >> 3;            // 32 f-subranges
    int tok0 = blockIdx.x * TB + tg * 4;

    float4 qa[4], qb[4];
#pragma unroll
    for (int k = 0; k < 4; ++k) {
        const float4* qr = (const float4*)(outq + (size_t)(tok0 + k) * EMB);
        qa[k] = qr[0];
        qb[k] = qr[1];
    }

    float acc[4][8];
#pragma unroll
    for (int k = 0; k < 4; ++k)
#pragma unroll
        for (int e = 0; e < 8; ++e) acc[k][e] = 0.f;

    int f0 = sub * FCH;
#pragma unroll 2
    for (int i = 0; i < FCH; ++i) {
        int f = f0 + i;
        const float4* w1r = (const float4*)(W1 + (size_t)f * EMB);
        float4 wa = w1r[0], wb = w1r[1];
        float bias = bb1[f];
        const float4* w2r = (const float4*)(w2t + (size_t)f * EMB);
        float4 va = w2r[0], vb = w2r[1];
#pragma unroll
        for (int k = 0; k < 4; ++k) {
            float hv = fmaxf(dot8(qa[k], wa, qb[k], wb) + bias, 0.f);
            acc[k][0] = fmaf(hv, va.x, acc[k][0]);
            acc[k][1] = fmaf(hv, va.y, acc[k][1]);
            acc[k][2] = fmaf(hv, va.z, acc[k][2]);
            acc[k][3] = fmaf(hv, va.w, acc[k][3]);
            acc[k][4] = fmaf(hv, vb.x, acc[k][4]);
            acc[k][5] = fmaf(hv, vb.y, acc[k][5]);
            acc[k][6] = fmaf(hv, vb.z, acc[k][6]);
            acc[k][7] = fmaf(hv, vb.w, acc[k][7]);
        }
    }
#pragma unroll
    for (int k = 0; k < 4; ++k) {
        float4* dst = (float4*)&red[sub][tg * 4 + k][0];
        dst[0] = make_float4(acc[k][0], acc[k][1], acc[k][2], acc[k][3]);
        dst[1] = make_float4(acc[k][4], acc[k][5], acc[k][6], acc[k][7]);
    }
    __syncthreads();

    int rtok = threadIdx.x >> 3;
    int re   = threadIdx.x & 7;
    float v = 0.f;
#pragma unroll
    for (int s = 0; s < NSUB; ++s) v += red[s][rtok][re];
    int tok = blockIdx.x * TB + rtok;
    v += bb2[re] + x1[(size_t)tok * EMB + re];

    float s8 = v;
    s8 += __shfl_xor(s8, 1);
    s8 += __shfl_xor(s8, 2);
    s8 += __shfl_xor(s8, 4);
    float mu = s8 * 0.125f;
    float d  = v - mu;
    float vs = d * d;
    vs += __shfl_xor(vs, 1);
    vs += __shfl_xor(vs, 2);
    vs += __shfl_xor(vs, 4);
    float r = rsqrtf(vs * 0.125f + LNEPS);
    out[(size_t)tok * EMB + re] = d * r * g2[re] + b2[re];
}

// ---------------------------------------------------------------------------
extern "C" void kernel_launch(void* const* d_in, const int* in_sizes, int n_in,
                              void* d_out, int out_size, void* d_ws, size_t ws_size,
                              hipStream_t stream) {
    const float* x   = (const float*)d_in[0];
    const float* Wp  = (const float*)d_in[1];
    const float* Wo  = (const float*)d_in[2];
    const float* g1  = (const float*)d_in[3];
    const float* b1  = (const float*)d_in[4];
    const float* W1  = (const float*)d_in[5];
    const float* bb1 = (const float*)d_in[6];
    const float* W2  = (const float*)d_in[7];
    const float* bb2 = (const float*)d_in[8];
    const float* g2  = (const float*)d_in[9];
    const float* b2  = (const float*)d_in[10];
    float* out = (float*)d_out;

    float* ws    = (float*)d_ws;
    float* projH = ws;                // 131072 f32 (head-major)
    float* ctx   = ws + 131072;       // 131072 f32
    float* x1    = ws + 262144;       // 131072 f32
    float* outq  = ws + 393216;       // 131072 f32
    float* w2t   = ws + 524288;       // 16384 f32

    hipLaunchKernelGGL(k_prep, dim3(NTOK / 256), dim3(256), 0, stream,
                       x, Wp, W2, projH, w2t);
    hipLaunchKernelGGL(k_attn, dim3(NB * NH * (SEQ / QC)), dim3(256), 0, stream,
                       projH, ctx);
    hipLaunchKernelGGL(k_post, dim3(NTOK / 256), dim3(256), 0, stream,
                       ctx, x, Wo, g1, b1, x1, outq);
    hipLaunchKernelGGL(k_ffn, dim3(NTOK / TB), dim3(256), 0, stream,
                       outq, x1, W1, bb1, w2t, bb2, g2, b2, out);
}